// Round 5
// baseline (474.463 us; speedup 1.0000x reference)
//
#include <hip/hip_runtime.h>
#include <hip/hip_bf16.h>

// StyleGAN2 modulated conv, fp32 in/out, bf16 MFMA implicit GEMM (NHWC).
// b=16, c_in=256, c_out=256, h=w=64, k=3.
#define BATCH 16
#define CIN   256
#define COUT  256
#define HH    64
#define WW    64
#define SDIM  512
#define NPIX  4096
#define PADH  66
#define PADW  66

typedef __hip_bfloat16 bf16;
typedef __attribute__((ext_vector_type(8))) short short8;   // 8 bf16
typedef __attribute__((ext_vector_type(4))) float f32x4;

__device__ __forceinline__ void glds16(const void* g, void* l) {
    __builtin_amdgcn_global_load_lds(
        (const __attribute__((address_space(1))) unsigned int*)g,
        (__attribute__((address_space(3))) unsigned int*)l, 16, 0, 0);
}

#define BAR()   __builtin_amdgcn_s_barrier()
#define VM0()   asm volatile("s_waitcnt vmcnt(0)" ::: "memory")
#define VM4()   asm volatile("s_waitcnt vmcnt(4)" ::: "memory")

// ---------------------------------------------------------------------------
// P1: s[b][ci] = dot(w_style[b,:], aff_w[ci,:]) + aff_b[ci] + 1
// ---------------------------------------------------------------------------
__global__ __launch_bounds__(256) void style_kernel(
    const float* __restrict__ w_style, const float* __restrict__ aff_w,
    const float* __restrict__ aff_b, float* __restrict__ s)
{
    const int b = blockIdx.x, c = threadIdx.x;
    __shared__ float ws[SDIM];
    for (int j = c; j < SDIM; j += 256) ws[j] = w_style[b * SDIM + j];
    __syncthreads();
    const float* aw = aff_w + (size_t)c * SDIM;
    float acc = 0.f;
#pragma unroll 4
    for (int j = 0; j < SDIM; j += 4) {
        const float4 a = *(const float4*)(aw + j);
        acc += a.x * ws[j] + a.y * ws[j + 1] + a.z * ws[j + 2] + a.w * ws[j + 3];
    }
    s[b * CIN + c] = acc + aff_b[c] + 1.0f;
}

// ---------------------------------------------------------------------------
// P2 fused: blocks [0,4096) = weight mod/demod -> wt[b][r][co][ci] bf16
//           blocks [4096,5152) = x NCHW fp32 -> xt[b][66][66][ci] bf16 (zero halo)
// ---------------------------------------------------------------------------
__global__ __launch_bounds__(256) void prep_kernel(
    const float* __restrict__ W, const float* __restrict__ s,
    const float* __restrict__ x,
    bf16* __restrict__ wt, bf16* __restrict__ xt)
{
    __shared__ union {
        float wl[CIN * 9];          // 9.2 KB (wgt part)
        bf16  t[WW][CIN + 2];       // 33 KB  (xpose part)
        float red4[4];
    } sh;
    const int tid = threadIdx.x;

    if (blockIdx.x < BATCH * COUT) {
        // ---- weight branch: one block per (b,co) ----
        const int bc = blockIdx.x, b = bc >> 8, co = bc & 255, ci = tid;
        const float* wrow = W + (size_t)co * (CIN * 9);
        for (int i = ci; i < CIN * 9 / 4; i += 256)
            *(float4*)&sh.wl[i * 4] = *(const float4*)(wrow + i * 4);
        __syncthreads();
        const float sv = s[b * CIN + ci];
        float m[9], part = 0.f;
#pragma unroll
        for (int r = 0; r < 9; ++r) { m[r] = sh.wl[ci * 9 + r] * sv; part += m[r] * m[r]; }
#pragma unroll
        for (int off = 32; off > 0; off >>= 1)
            part += __shfl_down(part, off, 64);
        __syncthreads();                    // protect union before re-use
        __shared__ float red[4];
        if ((ci & 63) == 0) red[ci >> 6] = part;
        __syncthreads();
        const float d = rsqrtf(red[0] + red[1] + red[2] + red[3] + 1e-8f);
#pragma unroll
        for (int r = 0; r < 9; ++r)
            wt[(((size_t)b * 9 + r) * COUT + co) * CIN + ci] = __float2bfloat16(m[r] * d);
    } else {
        // ---- transpose branch: one block per padded row ----
        const int xb  = blockIdx.x - BATCH * COUT;
        const int row = xb % PADH, b = xb / PADH;
        bf16* orow = xt + (((size_t)b * PADH + row) * PADW) * CIN;

        if (row == 0 || row == PADH - 1) {
            const uint4 z = {0, 0, 0, 0};
            for (int i = tid; i < PADW * CIN / 8; i += 256) ((uint4*)orow)[i] = z;
            return;
        }
        const float* xr = x + ((size_t)b * CIN * NPIX) + (size_t)(row - 1) * WW;
        // phase 1: float4 coalesced reads, transpose into LDS (stride 258 -> 2-way)
        for (int i = tid; i < CIN * (WW / 4); i += 256) {
            const int ci = i >> 4, c4 = (i & 15) * 4;
            const float4 v = *(const float4*)(xr + (size_t)ci * NPIX + c4);
            sh.t[c4 + 0][ci] = __float2bfloat16(v.x);
            sh.t[c4 + 1][ci] = __float2bfloat16(v.y);
            sh.t[c4 + 2][ci] = __float2bfloat16(v.z);
            sh.t[c4 + 3][ci] = __float2bfloat16(v.w);
        }
        __syncthreads();
        // phase 2: 8 bf16 per thread, uint4 global stores
        for (int i = tid; i < PADW * (CIN / 8); i += 256) {
            const int col = i >> 5, c8 = (i & 31) * 8;
            uint4 v = {0, 0, 0, 0};
            if (col > 0 && col < PADW - 1) {
                const unsigned* tp = (const unsigned*)&sh.t[col - 1][c8]; // 4B-aligned
                v.x = tp[0]; v.y = tp[1]; v.z = tp[2]; v.w = tp[3];
            }
            ((uint4*)orow)[i] = v;
        }
    }
}

// ---------------------------------------------------------------------------
// GEMM: out[b][co][px] = sum_{r,ci} wt[b][r][co][ci] * xt[b][y+dy+1][x+dx+1][ci]
// 8-phase 256x256 template (T1+T2+T3+T4+T5) adapted to conv:
//   block = 256co x 256px (4 pixel-rows), 8 waves, wave = 128co x 64px (8x4 frags)
//   Ash TRIPLE-buffered 3x32KB; stage A(s+2) at ph0; steady-state drain is
//   COUNTED vmcnt(4) at ph3 (retires only A(s+1), issued ~7 phases earlier;
//   A(s+2) stays in flight across the barrier -- T4). Full drains only at the
//   3 ci0 boundaries (B restage) and in the prologue.
//   T1: b = bid&15, nt = bid>>4 -> all 16 blocks sharing wt[b] land on one XCD
//   (bid%8 round-robin), so wt[b] is fetched ~once into that L2.
//   Staged-data visibility invariant: vmcnt -> s_barrier -> read.
// XOR swizzle identical to proven round-0 (16B chunk ^ (row&7), 128B rows).
// ---------------------------------------------------------------------------
__global__ __launch_bounds__(512, 2) void gemm_kernel(
    const bf16* __restrict__ xt,   // [B][66][66][256]
    const bf16* __restrict__ wt,   // [B][9][256][256]
    float* __restrict__ out)       // [B][256][4096]
{
    const int bid = blockIdx.x;
    const int b  = bid & 15;            // T1: same-b blocks share an XCD
    const int nt = bid >> 4;            // 4-row pixel group: rows nt*4 .. nt*4+3
    const int tid  = threadIdx.x;
    const int wave = tid >> 6, lane = tid & 63;
    const int wm = wave >> 2, wn = wave & 3;   // 2 x 4 wave grid
    const int lm = lane & 15, quad = lane >> 4;

    __shared__ bf16 Ash[3][256 * 64];   // 3 x 32 KB, [co][ci] swizzled
    __shared__ bf16 Bsh[6 * PADW * 64]; // 50.7 KB, [row*66+col][ci] swizzled

    f32x4 acc[8][4] = {};

    const bf16* xb = xt + (size_t)b * PADH * PADW * CIN;
    const bf16* wb = wt + (size_t)b * 9 * COUT * CIN;

    int p0[4];
#pragma unroll
    for (int ni = 0; ni < 4; ++ni)
        p0[ni] = (1 + wn) * PADW + ni * 16 + lm + 1;

    // ---- staging helpers (glds16: linear LDS dest, inverse-swizzled source) ----
    auto stageA = [&](int s2) {          // absolute step s2: r = s2%9, c = s2/9
        const int r = s2 % 9, c = s2 / 9, buf = s2 % 3;
        const bf16* wr = wb + (size_t)r * (COUT * CIN) + c * 64;
#pragma unroll
        for (int k = 0; k < 4; ++k) {
            const int i = tid + k * 512;
            const int co = i >> 3, pc = i & 7;
            const int lc = pc ^ (co & 7);
            glds16(wr + co * CIN + lc * 8, Ash[buf] + i * 8);
        }
    };
    auto stageB = [&](int c) {
        const int ci0 = c * 64;
        for (int i = tid; i < 6 * PADW * 8; i += 512) {
            const int row = i / (PADW * 8);
            const int j   = i - row * (PADW * 8);
            const int col = j >> 3, pc = j & 7;
            const int p   = row * PADW + col;
            const int lc  = pc ^ (p & 7);
            glds16(xb + (((size_t)(nt * 4 + row) * PADW + col) * CIN + ci0 + lc * 8),
                   Bsh + i * 8);
        }
    };
    auto readA = [&](short8* af, int kk, int mih, int buf) {
#pragma unroll
        for (int mi = 0; mi < 4; ++mi) {
            const int arow = wm * 128 + (mih * 4 + mi) * 16 + lm;
            const int lc   = kk * 4 + quad;
            af[mi] = *(const short8*)(Ash[buf] + arow * 64 + (lc ^ (arow & 7)) * 8);
        }
    };
    auto readB = [&](short8* bfr, int kk, int dpx) {
#pragma unroll
        for (int ni = 0; ni < 4; ++ni) {
            const int p  = p0[ni] + dpx;
            const int lc = kk * 4 + quad;
            bfr[ni] = *(const short8*)(Bsh + p * 64 + (lc ^ (p & 7)) * 8);
        }
    };
    auto mfma16 = [&](int half, const short8* af, const short8* bfr) {
        __builtin_amdgcn_s_setprio(1);
#pragma unroll
        for (int mi = 0; mi < 4; ++mi)
#pragma unroll
            for (int ni = 0; ni < 4; ++ni)
                acc[half * 4 + mi][ni] = __builtin_amdgcn_mfma_f32_16x16x32_bf16(
                    af[mi], bfr[ni], acc[half * 4 + mi][ni], 0, 0, 0);
        __builtin_amdgcn_s_setprio(0);
    };

    // ---- prologue: B(c=0) + A(step 0) + A(step 1); full drain; pre-read F0 ----
    stageB(0);
    stageA(0);
    stageA(1);
    __syncthreads();

    short8 afE[4], afO[4], bfE[4], bfO[4];
    readA(afE, 0, 0, 0);
    readB(bfE, 0, -PADW - 1);          // r=0: dy=-1, dx=-1

#pragma unroll 1
    for (int c = 0; c < 4; ++c) {
#pragma unroll 1
        for (int r = 0; r < 9; ++r) {
            const int s = c * 9 + r;
            const int cur = s % 3, nxt = (s + 1) % 3;
            const bool last = (s == 35);
            const int nr = (r == 8) ? 0 : r + 1;
            const int dpx  = (r / 3 - 1) * PADW + (r % 3 - 1);
            const int dpxn = (nr / 3 - 1) * PADW + (nr % 3 - 1);

            // phase 0: read F1 (afO: kk0, mi4-7); issue A(s+2) into buf (s+2)%3
            readA(afO, 0, 1, cur);
            if (s + 2 < 36) stageA(s + 2);
            BAR();
            mfma16(0, afE, bfE);        // kk0, acc half 0
            BAR();

            // phase 1: read F2 (afE: kk1 mi0-3; bfO: kk1)
            readA(afE, 1, 0, cur);
            readB(bfO, 1, dpx);
            BAR();
            mfma16(1, afO, bfE);        // kk0, acc half 1
            BAR();

            // phase 2: [B restage at tap boundary]; read F3 (afO: kk1 mi4-7)
            if (r == 8 && c < 3) {
                __syncthreads();        // all waves' old-B ds_reads retired + drain
                stageB(c + 1);
            }
            readA(afO, 1, 1, cur);
            BAR();
            mfma16(0, afE, bfO);        // kk1, acc half 0  (same acc as phase 0)
            BAR();

            // phase 3: wait staging -> barrier -> THEN pre-read next step's F0.
            //   steady state: counted vmcnt(4) retires A(s+1) (oldest 4 loads,
            //   ~7 phases old) while A(s+2) stays in flight across the barrier.
            //   boundary (r==8): full drain (covers freshly staged B(c+1)).
            if (last) {
                BAR();
                mfma16(1, afO, bfO);    // kk1, acc half 1
            } else {
                if (r == 8) VM0(); else VM4();
                BAR();
                readA(afE, 0, 0, nxt);
                readB(bfE, 0, dpxn);
                mfma16(1, afO, bfO);    // kk1, acc half 1  (same acc as phase 1)
                BAR();
            }
        }
    }

    // epilogue: C/D layout col=lane&15 (px), row=quad*4+v (co)
    float* ob = out + (size_t)b * COUT * NPIX + nt * 256;
#pragma unroll
    for (int mi = 0; mi < 8; ++mi) {
        const int cl = wm * 128 + mi * 16 + quad * 4;
#pragma unroll
        for (int ni = 0; ni < 4; ++ni) {
            const int px = wn * 64 + ni * 16 + lm;
#pragma unroll
            for (int v = 0; v < 4; ++v)
                ob[(size_t)(cl + v) * NPIX + px] = acc[mi][ni][v];
        }
    }
}

// ---------------------------------------------------------------------------
// Fallback (round-2, known correct) for small workspace.
// ---------------------------------------------------------------------------
template <bool FUSE_S>
__global__ __launch_bounds__(256) void conv_mod_kernel(
    const float* __restrict__ x, const float* __restrict__ W,
    const float* __restrict__ s_pre, const float* __restrict__ w_style,
    const float* __restrict__ aff_w, const float* __restrict__ aff_b,
    float* __restrict__ out)
{
    const int bc = blockIdx.x, b = bc >> 8, co = bc & 255, tid = threadIdx.x;
    __shared__ float wsh[CIN * 9];
    __shared__ float red[CIN];
    float sv;
    if (FUSE_S) {
        __shared__ float wst[SDIM];
        for (int j = tid; j < SDIM; j += 256) wst[j] = w_style[b * SDIM + j];
        __syncthreads();
        const float* aw = aff_w + tid * SDIM;
        float a2 = 0.f;
#pragma unroll 8
        for (int j = 0; j < SDIM; ++j) a2 += wst[j] * aw[j];
        sv = a2 + aff_b[tid] + 1.0f;
    } else sv = s_pre[b * CIN + tid];
    {
        const float* wp = W + (co * CIN + tid) * 9;
        float m[9], part = 0.f;
#pragma unroll
        for (int r = 0; r < 9; ++r) { m[r] = wp[r] * sv; part += m[r] * m[r]; }
        red[tid] = part;
        __syncthreads();
#pragma unroll
        for (int off = CIN / 2; off > 0; off >>= 1) {
            if (tid < off) red[tid] += red[tid + off];
            __syncthreads();
        }
        const float d = rsqrtf(red[0] + 1e-8f);
#pragma unroll
        for (int r = 0; r < 9; ++r) wsh[tid * 9 + r] = m[r] * d;
        __syncthreads();
    }
    const int p = blockIdx.y * 256 + tid, y = p >> 6, xx = p & 63;
    const bool vt = y > 0, vb = y < HH - 1, vl = xx > 0, vr = xx < WW - 1;
    const bool val[9] = { vt && vl, vt, vt && vr, vl, true, vr, vb && vl, vb, vb && vr };
    const int off9[9] = { -WW - 1, -WW, -WW + 1, -1, 0, 1, WW - 1, WW, WW + 1 };
    const float* xbp = x + (size_t)b * CIN * NPIX + p;
    float acc = 0.f;
    for (int ci = 0; ci < CIN; ++ci) {
        const float* xp = xbp + ci * NPIX;
        const float* wp = wsh + ci * 9;
#pragma unroll
        for (int r = 0; r < 9; ++r) acc += (val[r] ? xp[off9[r]] : 0.f) * wp[r];
    }
    out[(size_t)bc * NPIX + p] = acc;
}

// ---------------------------------------------------------------------------
extern "C" void kernel_launch(void* const* d_in, const int* in_sizes, int n_in,
                              void* d_out, int out_size, void* d_ws, size_t ws_size,
                              hipStream_t stream) {
    const float* x       = (const float*)d_in[0];
    const float* w_style = (const float*)d_in[1];
    const float* W       = (const float*)d_in[2];
    const float* aff_w   = (const float*)d_in[3];
    const float* aff_b   = (const float*)d_in[4];
    float* out = (float*)d_out;

    const size_t wt_off  = 65536;
    const size_t wt_sz   = (size_t)BATCH * 9 * COUT * CIN * sizeof(bf16);
    const size_t xt_off  = wt_off + wt_sz;
    const size_t xt_sz   = (size_t)BATCH * PADH * PADW * CIN * sizeof(bf16);
    const size_t need    = xt_off + xt_sz;

    if (ws_size >= need) {
        float* s  = (float*)d_ws;
        bf16* wt  = (bf16*)((char*)d_ws + wt_off);
        bf16* xt  = (bf16*)((char*)d_ws + xt_off);
        style_kernel<<<dim3(BATCH), dim3(256), 0, stream>>>(w_style, aff_w, aff_b, s);
        prep_kernel<<<dim3(BATCH * COUT + BATCH * PADH), dim3(256), 0, stream>>>(
            W, s, x, wt, xt);
        gemm_kernel<<<dim3(BATCH * 16), dim3(512), 0, stream>>>(xt, wt, out);
    } else if (ws_size >= (size_t)(BATCH * CIN * sizeof(float))) {
        float* s = (float*)d_ws;
        style_kernel<<<dim3(BATCH), dim3(256), 0, stream>>>(w_style, aff_w, aff_b, s);
        conv_mod_kernel<false><<<dim3(BATCH * COUT, NPIX / 256), dim3(256), 0, stream>>>(
            x, W, s, w_style, aff_w, aff_b, out);
    } else {
        conv_mod_kernel<true><<<dim3(BATCH * COUT, NPIX / 256), dim3(256), 0, stream>>>(
            x, W, nullptr, w_style, aff_w, aff_b, out);
    }
}

// Round 6
// 220.975 us; speedup vs baseline: 2.1471x; 2.1471x over previous
//
#include <hip/hip_runtime.h>
#include <hip/hip_bf16.h>

// StyleGAN2 modulated conv, fp32 in/out, bf16 MFMA implicit GEMM (NHWC).
// b=16, c_in=256, c_out=256, h=w=64, k=3.
#define BATCH 16
#define CIN   256
#define COUT  256
#define HH    64
#define WW    64
#define SDIM  512
#define NPIX  4096
#define PADH  66
#define PADW  66

typedef __hip_bfloat16 bf16;
typedef __attribute__((ext_vector_type(8))) short short8;   // 8 bf16
typedef __attribute__((ext_vector_type(4))) float f32x4;

__device__ __forceinline__ void glds16(const void* g, void* l) {
    __builtin_amdgcn_global_load_lds(
        (const __attribute__((address_space(1))) unsigned int*)g,
        (__attribute__((address_space(3))) unsigned int*)l, 16, 0, 0);
}

#define BAR()   __builtin_amdgcn_s_barrier()
#define VM0()   asm volatile("s_waitcnt vmcnt(0)" ::: "memory")

// ---------------------------------------------------------------------------
// P1: s[b][ci] = dot(w_style[b,:], aff_w[ci,:]) + aff_b[ci] + 1
// ---------------------------------------------------------------------------
__global__ __launch_bounds__(256) void style_kernel(
    const float* __restrict__ w_style, const float* __restrict__ aff_w,
    const float* __restrict__ aff_b, float* __restrict__ s)
{
    const int b = blockIdx.x, c = threadIdx.x;
    __shared__ float ws[SDIM];
    for (int j = c; j < SDIM; j += 256) ws[j] = w_style[b * SDIM + j];
    __syncthreads();
    const float* aw = aff_w + (size_t)c * SDIM;
    float acc = 0.f;
#pragma unroll 4
    for (int j = 0; j < SDIM; j += 4) {
        const float4 a = *(const float4*)(aw + j);
        acc += a.x * ws[j] + a.y * ws[j + 1] + a.z * ws[j + 2] + a.w * ws[j + 3];
    }
    s[b * CIN + c] = acc + aff_b[c] + 1.0f;
}

// ---------------------------------------------------------------------------
// P2 fused: blocks [0,4096) = weight mod/demod -> wt[b][r][co][ci] bf16
//           blocks [4096,5152) = x NCHW fp32 -> xt[b][66][66][ci] bf16 (zero halo)
// ---------------------------------------------------------------------------
__global__ __launch_bounds__(256) void prep_kernel(
    const float* __restrict__ W, const float* __restrict__ s,
    const float* __restrict__ x,
    bf16* __restrict__ wt, bf16* __restrict__ xt)
{
    __shared__ union {
        float wl[CIN * 9];          // 9.2 KB (wgt part)
        bf16  t[WW][CIN + 2];       // 33 KB  (xpose part)
        float red4[4];
    } sh;
    const int tid = threadIdx.x;

    if (blockIdx.x < BATCH * COUT) {
        // ---- weight branch: one block per (b,co) ----
        const int bc = blockIdx.x, b = bc >> 8, co = bc & 255, ci = tid;
        const float* wrow = W + (size_t)co * (CIN * 9);
        for (int i = ci; i < CIN * 9 / 4; i += 256)
            *(float4*)&sh.wl[i * 4] = *(const float4*)(wrow + i * 4);
        __syncthreads();
        const float sv = s[b * CIN + ci];
        float m[9], part = 0.f;
#pragma unroll
        for (int r = 0; r < 9; ++r) { m[r] = sh.wl[ci * 9 + r] * sv; part += m[r] * m[r]; }
#pragma unroll
        for (int off = 32; off > 0; off >>= 1)
            part += __shfl_down(part, off, 64);
        __syncthreads();                    // protect union before re-use
        __shared__ float red[4];
        if ((ci & 63) == 0) red[ci >> 6] = part;
        __syncthreads();
        const float d = rsqrtf(red[0] + red[1] + red[2] + red[3] + 1e-8f);
#pragma unroll
        for (int r = 0; r < 9; ++r)
            wt[(((size_t)b * 9 + r) * COUT + co) * CIN + ci] = __float2bfloat16(m[r] * d);
    } else {
        // ---- transpose branch: one block per padded row ----
        const int xb  = blockIdx.x - BATCH * COUT;
        const int row = xb % PADH, b = xb / PADH;
        bf16* orow = xt + (((size_t)b * PADH + row) * PADW) * CIN;

        if (row == 0 || row == PADH - 1) {
            const uint4 z = {0, 0, 0, 0};
            for (int i = tid; i < PADW * CIN / 8; i += 256) ((uint4*)orow)[i] = z;
            return;
        }
        const float* xr = x + ((size_t)b * CIN * NPIX) + (size_t)(row - 1) * WW;
        // phase 1: float4 coalesced reads, transpose into LDS (stride 258 -> 2-way)
        for (int i = tid; i < CIN * (WW / 4); i += 256) {
            const int ci = i >> 4, c4 = (i & 15) * 4;
            const float4 v = *(const float4*)(xr + (size_t)ci * NPIX + c4);
            sh.t[c4 + 0][ci] = __float2bfloat16(v.x);
            sh.t[c4 + 1][ci] = __float2bfloat16(v.y);
            sh.t[c4 + 2][ci] = __float2bfloat16(v.z);
            sh.t[c4 + 3][ci] = __float2bfloat16(v.w);
        }
        __syncthreads();
        // phase 2: 8 bf16 per thread, uint4 global stores
        for (int i = tid; i < PADW * (CIN / 8); i += 256) {
            const int col = i >> 5, c8 = (i & 31) * 8;
            uint4 v = {0, 0, 0, 0};
            if (col > 0 && col < PADW - 1) {
                const unsigned* tp = (const unsigned*)&sh.t[col - 1][c8]; // 4B-aligned
                v.x = tp[0]; v.y = tp[1]; v.z = tp[2]; v.w = tp[3];
            }
            ((uint4*)orow)[i] = v;
        }
    }
}

// ---------------------------------------------------------------------------
// GEMM: out[b][co][px] = sum_{r,ci} wt[b][r][co][ci] * xt[b][y+dy+1][x+dx+1][ci]
// Round-6 = EXACT round-4 schedule (proven 85.4us, VGPR 116, no spill) plus
// ONLY the T1 bid-decode swap:
//   b = bid&15, nt = bid>>4  ->  bid%8 == b%8, so all 16 blocks sharing wt[b]
//   land on one XCD (round-robin dispatch) and wt[b] (1.18 MB) is fetched ~once
//   into that XCD's L2 (round-5 measured: FETCH 99 -> 69 MB). With wt
//   L2-resident, the per-step VM0 drain (loads ~3 phases old) is near-free.
// Round-5's 3-buffer/counted-vmcnt variant spilled to scratch (VGPR capped at
// 128, WRITE_SIZE 774 MB) and is reverted wholesale.
//   block = 256co x 256px (4 pixel-rows), 8 waves, wave = 128co x 64px
//   Ash dbuf 2x32KB (A restages per r), Bsh 6x66x64 (reused across all 9 taps)
//   per r-step: 4 phases x 16 MFMA; raw s_barrier pairs; A(r+1) issued at ph0,
//   drained at ph3. Visibility invariant: vmcnt(0) -> s_barrier -> read.
// XOR swizzle identical to proven round-0 (16B chunk ^ (row&7), 128B rows).
// ---------------------------------------------------------------------------
__global__ __launch_bounds__(512, 2) void gemm_kernel(
    const bf16* __restrict__ xt,   // [B][66][66][256]
    const bf16* __restrict__ wt,   // [B][9][256][256]
    float* __restrict__ out)       // [B][256][4096]
{
    const int bid = blockIdx.x;
    const int b  = bid & 15;            // T1: same-b blocks share an XCD
    const int nt = bid >> 4;            // 4-row pixel group: rows nt*4 .. nt*4+3
    const int tid  = threadIdx.x;
    const int wave = tid >> 6, lane = tid & 63;
    const int wm = wave >> 2, wn = wave & 3;   // 2 x 4 wave grid
    const int lm = lane & 15, quad = lane >> 4;

    __shared__ bf16 Ash[2][256 * 64];   // 2 x 32 KB, [co][ci] swizzled
    __shared__ bf16 Bsh[6 * PADW * 64]; // 50.7 KB, [row*66+col][ci] swizzled

    f32x4 acc[8][4] = {};

    const bf16* xb = xt + (size_t)b * PADH * PADW * CIN;
    const bf16* wb = wt + (size_t)b * 9 * COUT * CIN;

    int p0[4];
#pragma unroll
    for (int ni = 0; ni < 4; ++ni)
        p0[ni] = (1 + wn) * PADW + ni * 16 + lm + 1;

    // ---- staging helpers (glds16: linear LDS dest, inverse-swizzled source) ----
    auto stageA = [&](int r, int c, int buf) {
        const bf16* wr = wb + (size_t)r * (COUT * CIN) + c * 64;
#pragma unroll
        for (int k = 0; k < 4; ++k) {
            const int i = tid + k * 512;
            const int co = i >> 3, pc = i & 7;
            const int lc = pc ^ (co & 7);
            glds16(wr + co * CIN + lc * 8, Ash[buf] + i * 8);
        }
    };
    auto stageB = [&](int c) {
        const int ci0 = c * 64;
        for (int i = tid; i < 6 * PADW * 8; i += 512) {
            const int row = i / (PADW * 8);
            const int j   = i - row * (PADW * 8);
            const int col = j >> 3, pc = j & 7;
            const int p   = row * PADW + col;
            const int lc  = pc ^ (p & 7);
            glds16(xb + (((size_t)(nt * 4 + row) * PADW + col) * CIN + ci0 + lc * 8),
                   Bsh + i * 8);
        }
    };
    auto readA = [&](short8* af, int kk, int mih, int buf) {
#pragma unroll
        for (int mi = 0; mi < 4; ++mi) {
            const int arow = wm * 128 + (mih * 4 + mi) * 16 + lm;
            const int lc   = kk * 4 + quad;
            af[mi] = *(const short8*)(Ash[buf] + arow * 64 + (lc ^ (arow & 7)) * 8);
        }
    };
    auto readB = [&](short8* bfr, int kk, int dpx) {
#pragma unroll
        for (int ni = 0; ni < 4; ++ni) {
            const int p  = p0[ni] + dpx;
            const int lc = kk * 4 + quad;
            bfr[ni] = *(const short8*)(Bsh + p * 64 + (lc ^ (p & 7)) * 8);
        }
    };
    auto mfma16 = [&](int half, const short8* af, const short8* bfr) {
        __builtin_amdgcn_s_setprio(1);
#pragma unroll
        for (int mi = 0; mi < 4; ++mi)
#pragma unroll
            for (int ni = 0; ni < 4; ++ni)
                acc[half * 4 + mi][ni] = __builtin_amdgcn_mfma_f32_16x16x32_bf16(
                    af[mi], bfr[ni], acc[half * 4 + mi][ni], 0, 0, 0);
        __builtin_amdgcn_s_setprio(0);
    };

    // ---- prologue: B(c=0) + A(r=0,c=0) -> Ash[0]; full drain; pre-read F0 ----
    stageB(0);
    stageA(0, 0, 0);
    __syncthreads();

    short8 afE[4], afO[4], bfE[4], bfO[4];
    readA(afE, 0, 0, 0);
    readB(bfE, 0, -PADW - 1);          // r=0: dy=-1, dx=-1

    int cur = 0;
#pragma unroll 1
    for (int c = 0; c < 4; ++c) {
#pragma unroll 1
        for (int r = 0; r < 9; ++r) {
            const bool last = (c == 3) && (r == 8);
            const int nr = (r == 8) ? 0 : r + 1;
            const int dpx  = (r / 3 - 1) * PADW + (r % 3 - 1);
            const int dpxn = (nr / 3 - 1) * PADW + (nr % 3 - 1);

            // phase 0: read F1 (afO: kk0, mi4-7); issue A(next) into Ash[cur^1]
            readA(afO, 0, 1, cur);
            if (!last) stageA(nr, (r == 8) ? c + 1 : c, cur ^ 1);
            BAR();
            mfma16(0, afE, bfE);        // kk0, acc half 0
            BAR();

            // phase 1: read F2 (afE: kk1 mi0-3; bfO: kk1)
            readA(afE, 1, 0, cur);
            readB(bfO, 1, dpx);
            BAR();
            mfma16(1, afO, bfE);        // kk0, acc half 1
            BAR();

            // phase 2: [B restage at tap boundary]; read F3 (afO: kk1 mi4-7)
            if (r == 8 && c < 3) {
                __syncthreads();        // all waves' old-B ds_reads retired + drain
                stageB(c + 1);
            }
            readA(afO, 1, 1, cur);
            BAR();
            mfma16(0, afE, bfO);        // kk1, acc half 0  (same acc as phase 0)
            BAR();

            // phase 3: drain staged A(next)[+B(next)] -> barrier -> THEN read F0'
            if (!last) VM0();
            BAR();
            if (!last) {
                readA(afE, 0, 0, cur ^ 1);
                readB(bfE, 0, dpxn);
            }
            mfma16(1, afO, bfO);        // kk1, acc half 1  (same acc as phase 1)
            BAR();
            cur ^= 1;
        }
    }

    // epilogue: C/D layout col=lane&15 (px), row=quad*4+v (co)
    float* ob = out + (size_t)b * COUT * NPIX + nt * 256;
#pragma unroll
    for (int mi = 0; mi < 8; ++mi) {
        const int cl = wm * 128 + mi * 16 + quad * 4;
#pragma unroll
        for (int ni = 0; ni < 4; ++ni) {
            const int px = wn * 64 + ni * 16 + lm;
#pragma unroll
            for (int v = 0; v < 4; ++v)
                ob[(size_t)(cl + v) * NPIX + px] = acc[mi][ni][v];
        }
    }
}

// ---------------------------------------------------------------------------
// Fallback (round-2, known correct) for small workspace.
// ---------------------------------------------------------------------------
template <bool FUSE_S>
__global__ __launch_bounds__(256) void conv_mod_kernel(
    const float* __restrict__ x, const float* __restrict__ W,
    const float* __restrict__ s_pre, const float* __restrict__ w_style,
    const float* __restrict__ aff_w, const float* __restrict__ aff_b,
    float* __restrict__ out)
{
    const int bc = blockIdx.x, b = bc >> 8, co = bc & 255, tid = threadIdx.x;
    __shared__ float wsh[CIN * 9];
    __shared__ float red[CIN];
    float sv;
    if (FUSE_S) {
        __shared__ float wst[SDIM];
        for (int j = tid; j < SDIM; j += 256) wst[j] = w_style[b * SDIM + j];
        __syncthreads();
        const float* aw = aff_w + tid * SDIM;
        float a2 = 0.f;
#pragma unroll 8
        for (int j = 0; j < SDIM; ++j) a2 += wst[j] * aw[j];
        sv = a2 + aff_b[tid] + 1.0f;
    } else sv = s_pre[b * CIN + tid];
    {
        const float* wp = W + (co * CIN + tid) * 9;
        float m[9], part = 0.f;
#pragma unroll
        for (int r = 0; r < 9; ++r) { m[r] = wp[r] * sv; part += m[r] * m[r]; }
        red[tid] = part;
        __syncthreads();
#pragma unroll
        for (int off = CIN / 2; off > 0; off >>= 1) {
            if (tid < off) red[tid] += red[tid + off];
            __syncthreads();
        }
        const float d = rsqrtf(red[0] + 1e-8f);
#pragma unroll
        for (int r = 0; r < 9; ++r) wsh[tid * 9 + r] = m[r] * d;
        __syncthreads();
    }
    const int p = blockIdx.y * 256 + tid, y = p >> 6, xx = p & 63;
    const bool vt = y > 0, vb = y < HH - 1, vl = xx > 0, vr = xx < WW - 1;
    const bool val[9] = { vt && vl, vt, vt && vr, vl, true, vr, vb && vl, vb, vb && vr };
    const int off9[9] = { -WW - 1, -WW, -WW + 1, -1, 0, 1, WW - 1, WW, WW + 1 };
    const float* xbp = x + (size_t)b * CIN * NPIX + p;
    float acc = 0.f;
    for (int ci = 0; ci < CIN; ++ci) {
        const float* xp = xbp + ci * NPIX;
        const float* wp = wsh + ci * 9;
#pragma unroll
        for (int r = 0; r < 9; ++r) acc += (val[r] ? xp[off9[r]] : 0.f) * wp[r];
    }
    out[(size_t)bc * NPIX + p] = acc;
}

// ---------------------------------------------------------------------------
extern "C" void kernel_launch(void* const* d_in, const int* in_sizes, int n_in,
                              void* d_out, int out_size, void* d_ws, size_t ws_size,
                              hipStream_t stream) {
    const float* x       = (const float*)d_in[0];
    const float* w_style = (const float*)d_in[1];
    const float* W       = (const float*)d_in[2];
    const float* aff_w   = (const float*)d_in[3];
    const float* aff_b   = (const float*)d_in[4];
    float* out = (float*)d_out;

    const size_t wt_off  = 65536;
    const size_t wt_sz   = (size_t)BATCH * 9 * COUT * CIN * sizeof(bf16);
    const size_t xt_off  = wt_off + wt_sz;
    const size_t xt_sz   = (size_t)BATCH * PADH * PADW * CIN * sizeof(bf16);
    const size_t need    = xt_off + xt_sz;

    if (ws_size >= need) {
        float* s  = (float*)d_ws;
        bf16* wt  = (bf16*)((char*)d_ws + wt_off);
        bf16* xt  = (bf16*)((char*)d_ws + xt_off);
        style_kernel<<<dim3(BATCH), dim3(256), 0, stream>>>(w_style, aff_w, aff_b, s);
        prep_kernel<<<dim3(BATCH * COUT + BATCH * PADH), dim3(256), 0, stream>>>(
            W, s, x, wt, xt);
        gemm_kernel<<<dim3(BATCH * 16), dim3(512), 0, stream>>>(xt, wt, out);
    } else if (ws_size >= (size_t)(BATCH * CIN * sizeof(float))) {
        float* s = (float*)d_ws;
        style_kernel<<<dim3(BATCH), dim3(256), 0, stream>>>(w_style, aff_w, aff_b, s);
        conv_mod_kernel<false><<<dim3(BATCH * COUT, NPIX / 256), dim3(256), 0, stream>>>(
            x, W, s, w_style, aff_w, aff_b, out);
    } else {
        conv_mod_kernel<true><<<dim3(BATCH * COUT, NPIX / 256), dim3(256), 0, stream>>>(
            x, W, nullptr, w_style, aff_w, aff_b, out);
    }
}